// Round 1
// baseline (407.294 us; speedup 1.0000x reference)
//
#include <hip/hip_runtime.h>
#include <math.h>

#define BB 8
#define CC 256
#define HH 128
#define WW 128
#define KK 16
#define GG 64
#define PP 16384  // H*W

// ---------------- ws layout (float offsets) ----------------
#define O_XNODE   0u          // B*C*H = 262144
#define O_T       262144u     // 262144
#define O_R       524288u     // 262144
#define O_CTX     786432u     // 262144
#define O_GT      1048576u    // 128*16384 = 2097152
#define O_ATTR    3145728u    // B*H*W = 131072
#define O_ATTC    3276800u    // 131072
#define O_UN      3407872u    // B*H*16 = 16384
#define O_SUP     3424256u    // B*H*64 = 65536
#define O_GOUT    3489792u    // 65536
#define O_VALS    3555328u    // B*H*8 = 8192
#define O_DEG     3563520u    // 1024
#define O_USUM    3564544u    // 1024
#define O_TMSUM   3565568u    // 1024
#define O_TM      3566592u    // 1024
#define O_SIGMT   3567616u    // 1024
#define O_ALPHA   3568640u    // 2048
#define O_SC      3570688u    // 2048
#define O_AROW    3572736u    // 1024
#define O_ACOL    3573760u    // 1024
#define O_IDX     3574784u    // 8192 ints
// total ~3583000 floats ~= 14.3 MB

__device__ __forceinline__ float bredSum256(float v, float* red) {
    int t = threadIdx.x, lane = t & 63, wv = t >> 6;
    for (int o = 32; o; o >>= 1) v += __shfl_xor(v, o);
    __syncthreads();
    if (lane == 0) red[wv] = v;
    __syncthreads();
    return red[0] + red[1] + red[2] + red[3];
}
__device__ __forceinline__ float bredMax256(float v, float* red) {
    int t = threadIdx.x, lane = t & 63, wv = t >> 6;
    for (int o = 32; o; o >>= 1) v = fmaxf(v, __shfl_xor(v, o));
    __syncthreads();
    if (lane == 0) red[wv] = v;
    __syncthreads();
    return fmaxf(fmaxf(red[0], red[1]), fmaxf(red[2], red[3]));
}

// ---------- Kernel A: X_node[b,c,h] = mean_w x ----------
__global__ __launch_bounds__(256) void kA(const float* __restrict__ x, float* __restrict__ Xnode) {
    int row = blockIdx.x * 4 + (threadIdx.x >> 6);   // row in [0, B*C*H)
    int lane = threadIdx.x & 63;
    const float2 v = *(const float2*)&x[(size_t)row * 128 + lane * 2];
    float s = v.x + v.y;
    for (int o = 32; o; o >>= 1) s += __shfl_down(s, o);
    if (lane == 0) Xnode[row] = s * (1.0f / 128.0f);
}

// ---------- S1: Un, Usum, support (per b,h) ----------
__global__ __launch_bounds__(64) void kS1(const float* __restrict__ U, const float* __restrict__ Xnode,
                                          const float* __restrict__ reduce_w, const float* __restrict__ gcn_w,
                                          float* __restrict__ Un, float* __restrict__ Usum, float* __restrict__ sup) {
    int bh = blockIdx.x; int b = bh >> 7, h = bh & 127;
    int t = threadIdx.x;
    __shared__ float xr[64];
    float u = (t < 16) ? U[bh * 16 + t] : 0.f;
    float ss = u * u;
    for (int o = 8; o; o >>= 1) ss += __shfl_xor(ss, o, 16);
    float us = u;
    for (int o = 8; o; o >>= 1) us += __shfl_xor(us, o, 16);
    if (t < 16) Un[bh * 16 + t] = u / fmaxf(sqrtf(ss), 1e-12f);
    if (t == 0) Usum[bh] = us;
    float acc = 0.f;
    #pragma unroll
    for (int m = 0; m < 4; ++m)
        acc = fmaf(Xnode[((b * CC + t * 4 + m) << 7) + h], reduce_w[t * 4 + m], acc);
    xr[t] = acc;
    __syncthreads();
    float sp = 0.f;
    for (int g = 0; g < 64; ++g) sp = fmaf(xr[g], gcn_w[g * 64 + t], sp);
    sup[bh * 64 + t] = sp;
}

// ---------- S2: sim row + top-8 + deg (per b,i) ----------
__global__ __launch_bounds__(128) void kS2(const float* __restrict__ Un, float* __restrict__ vals,
                                           int* __restrict__ idxv, float* __restrict__ deg) {
    int bh = blockIdx.x; int b = bh >> 7;
    int t = threadIdx.x;
    __shared__ float uni[16];
    __shared__ unsigned long long wmax[2];
    if (t < 16) uni[t] = Un[bh * 16 + t];
    __syncthreads();
    const float* uj = Un + (b << 11) + t * 16;
    float s = 0.f;
    #pragma unroll
    for (int q = 0; q < 16; ++q) s = fmaf(uni[q], uj[q], s);
    float dsum = 0.f;
    for (int r = 0; r < 8; ++r) {
        unsigned m = __float_as_uint(s);
        m = (m & 0x80000000u) ? ~m : (m | 0x80000000u);
        unsigned long long key = ((unsigned long long)m << 32) | (unsigned)(0xFFFFFFFFu - (unsigned)t);
        for (int o = 32; o; o >>= 1) { unsigned long long ok = __shfl_xor(key, o); key = key > ok ? key : ok; }
        if ((t & 63) == 0) wmax[t >> 6] = key;
        __syncthreads();
        unsigned long long kk = wmax[0] > wmax[1] ? wmax[0] : wmax[1];
        __syncthreads();
        int jw = (int)(0xFFFFFFFFu - (unsigned)(kk & 0xFFFFFFFFu));
        unsigned mm = (unsigned)(kk >> 32);
        mm = (mm & 0x80000000u) ? (mm & 0x7FFFFFFFu) : ~mm;
        float vw = __uint_as_float(mm);
        dsum += vw;
        if (t == r) { vals[bh * 8 + r] = vw; idxv[bh * 8 + r] = jw; }
        if (t == jw) s = -3.4e38f;
    }
    if (t == 0) deg[bh] = dsum;
}

// ---------- S3: gout, T, tmsum, sigmt (per b,i) ----------
__global__ __launch_bounds__(64) void kS3(const float* __restrict__ vals, const int* __restrict__ idxv,
                                          const float* __restrict__ deg, const float* __restrict__ sup,
                                          const float* __restrict__ gcn_b, const float* __restrict__ expand_w,
                                          float* __restrict__ gout, float* __restrict__ Tg,
                                          float* __restrict__ tmsum, float* __restrict__ sigmt) {
    int bh = blockIdx.x; int b = bh >> 7, i = bh & 127;
    int t = threadIdx.x;
    __shared__ float coef[8];
    __shared__ int id[8];
    if (t < 8) {
        int j = idxv[bh * 8 + t];
        float dv = vals[bh * 8 + t] * (1.f / sqrtf(deg[bh])) * (1.f / sqrtf(deg[(b << 7) + j]));
        coef[t] = dv; id[t] = j;
    }
    __syncthreads();
    float acc = gcn_b[t];
    #pragma unroll
    for (int q = 0; q < 8; ++q) acc = fmaf(coef[q], sup[((b << 7) + id[q]) * 64 + t], acc);
    float go = fmaxf(acc, 0.f);
    gout[bh * 64 + t] = go;
    float e0 = expand_w[t * 4], e1 = expand_w[t * 4 + 1], e2 = expand_w[t * 4 + 2], e3 = expand_w[t * 4 + 3];
    Tg[((b * CC + t * 4 + 0) << 7) + i] = go * e0;
    Tg[((b * CC + t * 4 + 1) << 7) + i] = go * e1;
    Tg[((b * CC + t * 4 + 2) << 7) + i] = go * e2;
    Tg[((b * CC + t * 4 + 3) << 7) + i] = go * e3;
    float tms = fabsf(go) * (fabsf(e0) + fabsf(e1) + fabsf(e2) + fabsf(e3));
    float mtp = go * (e0 + e1 + e2 + e3);
    for (int o = 32; o; o >>= 1) { tms += __shfl_down(tms, o); mtp += __shfl_down(mtp, o); }
    if (t == 0) {
        tmsum[bh] = tms;
        sigmt[bh] = 1.f / (1.f + expf(-(mtp * (1.f / 256.f))));
    }
}

// ---------- S4: tm, z's, ch_rec/sig, sc, w4 -> arow/acol/alpha (per b) ----------
__global__ __launch_bounds__(256) void kS4(const float* __restrict__ Xnode, const float* __restrict__ Tg,
                                           const float* __restrict__ V, const float* __restrict__ S,
                                           const float* __restrict__ boast, const float* __restrict__ res_scale,
                                           const float* __restrict__ w_row, const float* __restrict__ w_col,
                                           const float* __restrict__ tmsum,
                                           float* __restrict__ tm, float* __restrict__ alpha, float* __restrict__ sc,
                                           float* __restrict__ arow, float* __restrict__ acol) {
    int b = blockIdx.x; int t = threadIdx.x;
    __shared__ float red[4];
    __shared__ float zc[256];
    __shared__ float zk[16];
    // tm
    float tv = (t < 128) ? tmsum[(b << 7) + t] : -3.4e38f;
    float tmax = bredMax256(tv, red);
    if (t < 128) tm[(b << 7) + t] = tv / fmaxf(tmax, 1e-6f);
    // z_x, z_topo (c = t)
    const float* xn = Xnode + ((size_t)(b * CC + t) << 7);
    const float* tg = Tg + ((size_t)(b * CC + t) << 7);
    float zx = 0.f, zt = 0.f;
    for (int h = 0; h < 128; ++h) { zx += xn[h]; zt += tg[h]; }
    zx *= (1.f / 128.f); zt *= (1.f / 128.f);
    zc[t] = zx + 0.5f * zt;
    __syncthreads();
    if (t < 16) {
        float a = 0.f;
        for (int c = 0; c < 256; ++c) a = fmaf(zc[c], V[((b * CC + c) << 4) + t], a);
        zk[t] = a;
    }
    __syncthreads();
    float sumS = 0.f, sumz = 0.f;
    #pragma unroll
    for (int j = 0; j < 16; ++j) { sumS += S[(b << 4) + j]; sumz += zk[j]; }
    float Vz = 0.f, VS = 0.f;
    #pragma unroll
    for (int j = 0; j < 16; ++j) {
        float vv = V[((b * CC + t) << 4) + j];
        Vz = fmaf(vv, zk[j], Vz);
        VS = fmaf(vv, S[(b << 4) + j], VS);
    }
    float ch = (Vz * sumS + VS * sumz) * (1.f / 32.f);
    float sig = 1.f / (1.f + expf(-ch));
    // sc = softmax_c(z_topo)
    float zm = bredMax256(zt, red);
    float e = expf(zt - zm);
    float es = bredSum256(e, red);
    sc[b * CC + t] = e / es;
    // w4
    float ps = 0.f;
    for (int q = t; q < 272; q += 256) {
        float si = (q < 16) ? S[(b << 4) + q] : (q < 144 ? w_col[q - 16] : w_row[q - 144]);
        ps += si;
    }
    float ssum = bredSum256(ps, red);
    float l0 = ssum * boast[t];
    float l1 = ssum * boast[256 + t];
    float lm = bredMax256(fmaxf(l0, l1), red);
    float e0 = expf(l0 - lm), e1 = expf(l1 - lm);
    float esum = bredSum256(e0 + e1, red);
    float w40 = e0 / esum, w41 = e1 / esum;
    if (t < 128) arow[(b << 7) + t] = w40;
    else acol[(b << 7) + (t - 128)] = w40;
    alpha[b * CC + t] = res_scale[0] + w41 * sig;
}

// ---------- S5row: att_row[b,h,w] softmax over w ----------
__global__ __launch_bounds__(128) void kS5r(const float* __restrict__ Usum, const float* __restrict__ w_row,
                                            const float* __restrict__ tm, float* __restrict__ attr) {
    int bh = blockIdx.x;
    int w = threadIdx.x;
    __shared__ float red[2];
    float l = Usum[bh] * w_row[w] + 0.5f * tm[bh];
    float m = l;
    for (int o = 32; o; o >>= 1) m = fmaxf(m, __shfl_xor(m, o));
    if ((w & 63) == 0) red[w >> 6] = m;
    __syncthreads();
    m = fmaxf(red[0], red[1]);
    __syncthreads();
    float e = expf(l - m);
    float s = e;
    for (int o = 32; o; o >>= 1) s += __shfl_xor(s, o);
    if ((w & 63) == 0) red[w >> 6] = s;
    __syncthreads();
    s = red[0] + red[1];
    attr[bh * 128 + w] = e / s;
}

// ---------- S5col: att_col[b,h,w] softmax over h ----------
__global__ __launch_bounds__(128) void kS5c(const float* __restrict__ Usum, const float* __restrict__ w_col,
                                            const float* __restrict__ tm, float* __restrict__ attc) {
    int bw = blockIdx.x; int b = bw >> 7, w = bw & 127;
    int h = threadIdx.x;
    __shared__ float red[2];
    float l = Usum[(b << 7) + h] * w_col[w] + 0.5f * tm[(b << 7) + h];
    float m = l;
    for (int o = 32; o; o >>= 1) m = fmaxf(m, __shfl_xor(m, o));
    if ((h & 63) == 0) red[h >> 6] = m;
    __syncthreads();
    m = fmaxf(red[0], red[1]);
    __syncthreads();
    float e = expf(l - m);
    float s = e;
    for (int o = 32; o; o >>= 1) s += __shfl_xor(s, o);
    if ((h & 63) == 0) red[h >> 6] = s;
    __syncthreads();
    s = red[0] + red[1];
    attc[((b << 7) + h) * 128 + w] = e / s;
}

// ---------- kR: R[b,c,h], Cctx[b,c,w] (per b,c block) ----------
__global__ __launch_bounds__(128) void kR(const float* __restrict__ x, const float* __restrict__ attr,
                                          const float* __restrict__ attc, float* __restrict__ Rg,
                                          float* __restrict__ Cg) {
    int bc = blockIdx.x;          // b*C + c
    int b = bc >> 8;
    int w = threadIdx.x;
    int lane = w & 63, wv = w >> 6;
    __shared__ float rp[128][2];
    float cacc = 0.f;
    const float* xt = x + (size_t)bc * PP;
    const float* ar = attr + b * PP;
    const float* ac = attc + b * PP;
    for (int h = 0; h < 128; ++h) {
        float xv = xt[h * 128 + w];
        float arv = ar[h * 128 + w];
        float acv = ac[h * 128 + w];
        cacc = fmaf(acv, xv, cacc);
        float r = arv * xv;
        for (int o = 32; o; o >>= 1) r += __shfl_down(r, o);
        if (lane == 0) rp[h][wv] = r;
    }
    __syncthreads();
    Cg[bc * 128 + w] = cacc;
    Rg[bc * 128 + w] = rp[w][0] + rp[w][1];
}

// ---------- kGt: transpose G (P,K) -> Gt (K,P) ----------
__global__ __launch_bounds__(256) void kGt(const float* __restrict__ G, float* __restrict__ Gt) {
    __shared__ float tile[64][129];
    int p0 = blockIdx.x * 64;
    int t = threadIdx.x;
    for (int i = t; i < 8192; i += 256) {
        int pr = i >> 7, k = i & 127;
        tile[pr][k] = G[(size_t)(p0 + pr) * 128 + k];
    }
    __syncthreads();
    for (int i = t; i < 8192; i += 256) {
        int k = i >> 6, j = i & 63;
        Gt[(size_t)k * PP + p0 + j] = tile[j][k];
    }
}

// ---------- kF: fused GEMM (row_out/col_out) + epilogue ----------
__device__ __forceinline__ void fma4(float s, const float4& a, float4& acc) {
    acc.x = fmaf(s, a.x, acc.x);
    acc.y = fmaf(s, a.y, acc.y);
    acc.z = fmaf(s, a.z, acc.z);
    acc.w = fmaf(s, a.w, acc.w);
}

__global__ __launch_bounds__(256) void kF(const float* __restrict__ x, const float* __restrict__ Gt,
                                          const float* __restrict__ Rg, const float* __restrict__ Cg,
                                          const float* __restrict__ Tg, const float* __restrict__ alpha,
                                          const float* __restrict__ sc, const float* __restrict__ sigmt,
                                          const float* __restrict__ arow, const float* __restrict__ acol,
                                          float* __restrict__ out) {
    __shared__ float Rs[64][128];
    __shared__ float Cs[64][128];
    int b = blockIdx.z;
    int c0 = blockIdx.y * 64;
    int p0 = blockIdx.x * 64;
    int tid = threadIdx.x;
    for (int i = tid; i < 8192; i += 256) {
        int ci = i >> 7, k = i & 127;
        Rs[ci][k] = Rg[((b * CC + c0 + ci) << 7) + k];
        Cs[ci][k] = Cg[((b * CC + c0 + ci) << 7) + k];
    }
    __syncthreads();
    int tj = tid & 15, ti = tid >> 4;   // tj: p-group (4 p's), ti: c-group (4 c's)
    const float* gp = Gt + p0 + tj * 4;
    float4 a1[4], a2[4];
    #pragma unroll
    for (int i = 0; i < 4; ++i) { a1[i] = make_float4(0, 0, 0, 0); a2[i] = make_float4(0, 0, 0, 0); }
    for (int k = 0; k < 128; k += 4) {
        float4 g0 = *(const float4*)(gp + (size_t)(k + 0) * PP);
        float4 g1 = *(const float4*)(gp + (size_t)(k + 1) * PP);
        float4 g2 = *(const float4*)(gp + (size_t)(k + 2) * PP);
        float4 g3 = *(const float4*)(gp + (size_t)(k + 3) * PP);
        #pragma unroll
        for (int ci = 0; ci < 4; ++ci) {
            float4 r4 = *(const float4*)&Rs[ti * 4 + ci][k];
            float4 c4 = *(const float4*)&Cs[ti * 4 + ci][k];
            fma4(r4.x, g0, a1[ci]); fma4(r4.y, g1, a1[ci]); fma4(r4.z, g2, a1[ci]); fma4(r4.w, g3, a1[ci]);
            fma4(c4.x, g0, a2[ci]); fma4(c4.y, g1, a2[ci]); fma4(c4.z, g2, a2[ci]); fma4(c4.w, g3, a2[ci]);
        }
    }
    // epilogue
    int ph = p0 >> 7;                       // h uniform over the 64-p tile
    int wbase = (p0 & 127) + tj * 4;
    float ar = arow[(b << 7) + ph];
    float4 ac4 = *(const float4*)&acol[(b << 7) + wbase];
    float smt = sigmt[(b << 7) + ph];
    #pragma unroll
    for (int ci = 0; ci < 4; ++ci) {
        int c = c0 + ti * 4 + ci;
        float al = alpha[b * CC + c];
        float tb = (sc[b * CC + c] + smt) * Tg[((b * CC + c) << 7) + ph];
        const float4 xv = *(const float4*)&x[((size_t)(b * CC + c) << 14) + p0 + tj * 4];
        float4 o;
        o.x = fmaf(al, xv.x, fmaf(ar, a1[ci].x, fmaf(ac4.x, a2[ci].x, ar * ac4.x * tb)));
        o.y = fmaf(al, xv.y, fmaf(ar, a1[ci].y, fmaf(ac4.y, a2[ci].y, ar * ac4.y * tb)));
        o.z = fmaf(al, xv.z, fmaf(ar, a1[ci].z, fmaf(ac4.z, a2[ci].z, ar * ac4.z * tb)));
        o.w = fmaf(al, xv.w, fmaf(ar, a1[ci].w, fmaf(ac4.w, a2[ci].w, ar * ac4.w * tb)));
        *(float4*)&out[((size_t)(b * CC + c) << 14) + p0 + tj * 4] = o;
    }
}

extern "C" void kernel_launch(void* const* d_in, const int* in_sizes, int n_in,
                              void* d_out, int out_size, void* d_ws, size_t ws_size,
                              hipStream_t stream) {
    const float* x        = (const float*)d_in[0];
    const float* U        = (const float*)d_in[1];
    const float* S        = (const float*)d_in[2];
    const float* V        = (const float*)d_in[3];
    const float* G        = (const float*)d_in[4];
    const float* w_row    = (const float*)d_in[5];
    const float* w_col    = (const float*)d_in[6];
    const float* boast    = (const float*)d_in[7];
    const float* res_scale= (const float*)d_in[8];
    const float* reduce_w = (const float*)d_in[9];
    const float* gcn_w    = (const float*)d_in[10];
    const float* gcn_b    = (const float*)d_in[11];
    const float* expand_w = (const float*)d_in[12];
    float* ws = (float*)d_ws;
    float* out = (float*)d_out;

    float* Xnode = ws + O_XNODE;
    float* Tg    = ws + O_T;
    float* Rg    = ws + O_R;
    float* Cg    = ws + O_CTX;
    float* Gt    = ws + O_GT;
    float* attr  = ws + O_ATTR;
    float* attc  = ws + O_ATTC;
    float* Un    = ws + O_UN;
    float* sup   = ws + O_SUP;
    float* gout  = ws + O_GOUT;
    float* vals  = ws + O_VALS;
    float* deg   = ws + O_DEG;
    float* Usum  = ws + O_USUM;
    float* tmsum = ws + O_TMSUM;
    float* tm    = ws + O_TM;
    float* sigmt = ws + O_SIGMT;
    float* alpha = ws + O_ALPHA;
    float* sc    = ws + O_SC;
    float* arow  = ws + O_AROW;
    float* acol  = ws + O_ACOL;
    int*   idxv  = (int*)(ws + O_IDX);

    kGt<<<256, 256, 0, stream>>>(G, Gt);
    kA<<<BB * CC * HH / 4, 256, 0, stream>>>(x, Xnode);
    kS1<<<BB * HH, 64, 0, stream>>>(U, Xnode, reduce_w, gcn_w, Un, Usum, sup);
    kS2<<<BB * HH, 128, 0, stream>>>(Un, vals, idxv, deg);
    kS3<<<BB * HH, 64, 0, stream>>>(vals, idxv, deg, sup, gcn_b, expand_w, gout, Tg, tmsum, sigmt);
    kS4<<<BB, 256, 0, stream>>>(Xnode, Tg, V, S, boast, res_scale, w_row, w_col, tmsum,
                                tm, alpha, sc, arow, acol);
    kS5r<<<BB * HH, 128, 0, stream>>>(Usum, w_row, tm, attr);
    kS5c<<<BB * WW, 128, 0, stream>>>(Usum, w_col, tm, attc);
    kR<<<BB * CC, 128, 0, stream>>>(x, attr, attc, Rg, Cg);
    kF<<<dim3(PP / 64, CC / 64, BB), 256, 0, stream>>>(x, Gt, Rg, Cg, Tg, alpha, sc, sigmt,
                                                       arow, acol, out);
}

// Round 2
// 266.991 us; speedup vs baseline: 1.5255x; 1.5255x over previous
//
#include <hip/hip_runtime.h>
#include <math.h>

#define BB 8
#define CC 256
#define HH 128
#define WW 128
#define KK 16
#define GG 64
#define PP 16384  // H*W

typedef __attribute__((ext_vector_type(8))) short bf16x8;
typedef __attribute__((ext_vector_type(4))) float f32x4;

// ---------------- ws layout (float offsets) ----------------
#define O_XNODE   0u          // B*C*H = 262144
#define O_T       262144u     // 262144
#define O_R       524288u     // Rh bf16 (262144 ushort)
#define O_CTX     786432u     // Ch bf16
#define O_GT      1048576u    // Gb bf16 (2097152 ushort fits in 2097152 floats)
#define O_ATTR    3145728u    // B*H*W = 131072
#define O_ATTC    3276800u    // 131072
#define O_UN      3407872u    // B*H*16 = 16384
#define O_SUP     3424256u    // B*H*64 = 65536
#define O_GOUT    3489792u    // 65536
#define O_VALS    3555328u    // B*H*8 = 8192
#define O_DEG     3563520u    // 1024
#define O_USUM    3564544u    // 1024
#define O_TMSUM   3565568u    // 1024
#define O_TM      3566592u    // 1024
#define O_SIGMT   3567616u    // 1024
#define O_ALPHA   3568640u    // 2048
#define O_SC      3570688u    // 2048
#define O_AROW    3572736u    // 1024
#define O_ACOL    3573760u    // 1024
#define O_IDX     3574784u    // 8192 ints

__device__ __forceinline__ ushort f2b(float f) {
    unsigned u = __float_as_uint(f);
    unsigned r = (u + 0x7FFFu + ((u >> 16) & 1u)) >> 16;
    return (ushort)r;
}

__device__ __forceinline__ float bredSum256(float v, float* red) {
    int t = threadIdx.x, lane = t & 63, wv = t >> 6;
    for (int o = 32; o; o >>= 1) v += __shfl_xor(v, o);
    __syncthreads();
    if (lane == 0) red[wv] = v;
    __syncthreads();
    return red[0] + red[1] + red[2] + red[3];
}
__device__ __forceinline__ float bredMax256(float v, float* red) {
    int t = threadIdx.x, lane = t & 63, wv = t >> 6;
    for (int o = 32; o; o >>= 1) v = fmaxf(v, __shfl_xor(v, o));
    __syncthreads();
    if (lane == 0) red[wv] = v;
    __syncthreads();
    return fmaxf(fmaxf(red[0], red[1]), fmaxf(red[2], red[3]));
}

// ---------- Kernel A: X_node[b,c,h] = mean_w x ----------
__global__ __launch_bounds__(256) void kA(const float* __restrict__ x, float* __restrict__ Xnode) {
    int row = blockIdx.x * 4 + (threadIdx.x >> 6);
    int lane = threadIdx.x & 63;
    const float2 v = *(const float2*)&x[(size_t)row * 128 + lane * 2];
    float s = v.x + v.y;
    for (int o = 32; o; o >>= 1) s += __shfl_down(s, o);
    if (lane == 0) Xnode[row] = s * (1.0f / 128.0f);
}

// ---------- kGb: G (P,K) f32 -> bf16 (same layout) ----------
__global__ __launch_bounds__(256) void kGb(const float* __restrict__ G, ushort* __restrict__ Gb) {
    int i = (blockIdx.x * 256 + threadIdx.x) * 8;
    float4 v0 = *(const float4*)&G[i];
    float4 v1 = *(const float4*)&G[i + 4];
    union { ushort us[8]; uint4 u4; } o;
    o.us[0] = f2b(v0.x); o.us[1] = f2b(v0.y); o.us[2] = f2b(v0.z); o.us[3] = f2b(v0.w);
    o.us[4] = f2b(v1.x); o.us[5] = f2b(v1.y); o.us[6] = f2b(v1.z); o.us[7] = f2b(v1.w);
    *(uint4*)&Gb[i] = o.u4;
}

// ---------- S1: Un, Usum, support (per b,h) ----------
__global__ __launch_bounds__(64) void kS1(const float* __restrict__ U, const float* __restrict__ Xnode,
                                          const float* __restrict__ reduce_w, const float* __restrict__ gcn_w,
                                          float* __restrict__ Un, float* __restrict__ Usum, float* __restrict__ sup) {
    int bh = blockIdx.x; int b = bh >> 7, h = bh & 127;
    int t = threadIdx.x;
    __shared__ float xr[64];
    float u = (t < 16) ? U[bh * 16 + t] : 0.f;
    float ss = u * u;
    for (int o = 8; o; o >>= 1) ss += __shfl_xor(ss, o, 16);
    float us = u;
    for (int o = 8; o; o >>= 1) us += __shfl_xor(us, o, 16);
    if (t < 16) Un[bh * 16 + t] = u / fmaxf(sqrtf(ss), 1e-12f);
    if (t == 0) Usum[bh] = us;
    float acc = 0.f;
    #pragma unroll
    for (int m = 0; m < 4; ++m)
        acc = fmaf(Xnode[((b * CC + t * 4 + m) << 7) + h], reduce_w[t * 4 + m], acc);
    xr[t] = acc;
    __syncthreads();
    float sp = 0.f;
    for (int g = 0; g < 64; ++g) sp = fmaf(xr[g], gcn_w[g * 64 + t], sp);
    sup[bh * 64 + t] = sp;
}

// ---------- S2: sim row + top-8 + deg (per b,i) ----------
__global__ __launch_bounds__(128) void kS2(const float* __restrict__ Un, float* __restrict__ vals,
                                           int* __restrict__ idxv, float* __restrict__ deg) {
    int bh = blockIdx.x; int b = bh >> 7;
    int t = threadIdx.x;
    __shared__ float uni[16];
    __shared__ unsigned long long wmax[2];
    if (t < 16) uni[t] = Un[bh * 16 + t];
    __syncthreads();
    const float* uj = Un + (b << 11) + t * 16;
    float s = 0.f;
    #pragma unroll
    for (int q = 0; q < 16; ++q) s = fmaf(uni[q], uj[q], s);
    float dsum = 0.f;
    for (int r = 0; r < 8; ++r) {
        unsigned m = __float_as_uint(s);
        m = (m & 0x80000000u) ? ~m : (m | 0x80000000u);
        unsigned long long key = ((unsigned long long)m << 32) | (unsigned)(0xFFFFFFFFu - (unsigned)t);
        for (int o = 32; o; o >>= 1) { unsigned long long ok = __shfl_xor(key, o); key = key > ok ? key : ok; }
        if ((t & 63) == 0) wmax[t >> 6] = key;
        __syncthreads();
        unsigned long long kk = wmax[0] > wmax[1] ? wmax[0] : wmax[1];
        __syncthreads();
        int jw = (int)(0xFFFFFFFFu - (unsigned)(kk & 0xFFFFFFFFu));
        unsigned mm = (unsigned)(kk >> 32);
        mm = (mm & 0x80000000u) ? (mm & 0x7FFFFFFFu) : ~mm;
        float vw = __uint_as_float(mm);
        dsum += vw;
        if (t == r) { vals[bh * 8 + r] = vw; idxv[bh * 8 + r] = jw; }
        if (t == jw) s = -3.4e38f;
    }
    if (t == 0) deg[bh] = dsum;
}

// ---------- S3: gout, T, tmsum, sigmt (per b,i) ----------
__global__ __launch_bounds__(64) void kS3(const float* __restrict__ vals, const int* __restrict__ idxv,
                                          const float* __restrict__ deg, const float* __restrict__ sup,
                                          const float* __restrict__ gcn_b, const float* __restrict__ expand_w,
                                          float* __restrict__ gout, float* __restrict__ Tg,
                                          float* __restrict__ tmsum, float* __restrict__ sigmt) {
    int bh = blockIdx.x; int b = bh >> 7, i = bh & 127;
    int t = threadIdx.x;
    __shared__ float coef[8];
    __shared__ int id[8];
    if (t < 8) {
        int j = idxv[bh * 8 + t];
        float dv = vals[bh * 8 + t] * (1.f / sqrtf(deg[bh])) * (1.f / sqrtf(deg[(b << 7) + j]));
        coef[t] = dv; id[t] = j;
    }
    __syncthreads();
    float acc = gcn_b[t];
    #pragma unroll
    for (int q = 0; q < 8; ++q) acc = fmaf(coef[q], sup[((b << 7) + id[q]) * 64 + t], acc);
    float go = fmaxf(acc, 0.f);
    gout[bh * 64 + t] = go;
    float e0 = expand_w[t * 4], e1 = expand_w[t * 4 + 1], e2 = expand_w[t * 4 + 2], e3 = expand_w[t * 4 + 3];
    Tg[((b * CC + t * 4 + 0) << 7) + i] = go * e0;
    Tg[((b * CC + t * 4 + 1) << 7) + i] = go * e1;
    Tg[((b * CC + t * 4 + 2) << 7) + i] = go * e2;
    Tg[((b * CC + t * 4 + 3) << 7) + i] = go * e3;
    float tms = fabsf(go) * (fabsf(e0) + fabsf(e1) + fabsf(e2) + fabsf(e3));
    float mtp = go * (e0 + e1 + e2 + e3);
    for (int o = 32; o; o >>= 1) { tms += __shfl_down(tms, o); mtp += __shfl_down(mtp, o); }
    if (t == 0) {
        tmsum[bh] = tms;
        sigmt[bh] = 1.f / (1.f + expf(-(mtp * (1.f / 256.f))));
    }
}

// ---------- S4: tm, z's, ch_rec/sig, sc, w4 -> arow/acol/alpha (per b) ----------
__global__ __launch_bounds__(256) void kS4(const float* __restrict__ Xnode, const float* __restrict__ Tg,
                                           const float* __restrict__ V, const float* __restrict__ S,
                                           const float* __restrict__ boast, const float* __restrict__ res_scale,
                                           const float* __restrict__ w_row, const float* __restrict__ w_col,
                                           const float* __restrict__ tmsum,
                                           float* __restrict__ tm, float* __restrict__ alpha, float* __restrict__ sc,
                                           float* __restrict__ arow, float* __restrict__ acol) {
    int b = blockIdx.x; int t = threadIdx.x;
    __shared__ float red[4];
    __shared__ float zc[256];
    __shared__ float zk[16];
    float tv = (t < 128) ? tmsum[(b << 7) + t] : -3.4e38f;
    float tmax = bredMax256(tv, red);
    if (t < 128) tm[(b << 7) + t] = tv / fmaxf(tmax, 1e-6f);
    const float* xn = Xnode + ((size_t)(b * CC + t) << 7);
    const float* tg = Tg + ((size_t)(b * CC + t) << 7);
    float zx = 0.f, zt = 0.f;
    for (int h = 0; h < 128; ++h) { zx += xn[h]; zt += tg[h]; }
    zx *= (1.f / 128.f); zt *= (1.f / 128.f);
    zc[t] = zx + 0.5f * zt;
    __syncthreads();
    if (t < 16) {
        float a = 0.f;
        for (int c = 0; c < 256; ++c) a = fmaf(zc[c], V[((b * CC + c) << 4) + t], a);
        zk[t] = a;
    }
    __syncthreads();
    float sumS = 0.f, sumz = 0.f;
    #pragma unroll
    for (int j = 0; j < 16; ++j) { sumS += S[(b << 4) + j]; sumz += zk[j]; }
    float Vz = 0.f, VS = 0.f;
    #pragma unroll
    for (int j = 0; j < 16; ++j) {
        float vv = V[((b * CC + t) << 4) + j];
        Vz = fmaf(vv, zk[j], Vz);
        VS = fmaf(vv, S[(b << 4) + j], VS);
    }
    float ch = (Vz * sumS + VS * sumz) * (1.f / 32.f);
    float sig = 1.f / (1.f + expf(-ch));
    float zm = bredMax256(zt, red);
    float e = expf(zt - zm);
    float es = bredSum256(e, red);
    sc[b * CC + t] = e / es;
    float ps = 0.f;
    for (int q = t; q < 272; q += 256) {
        float si = (q < 16) ? S[(b << 4) + q] : (q < 144 ? w_col[q - 16] : w_row[q - 144]);
        ps += si;
    }
    float ssum = bredSum256(ps, red);
    float l0 = ssum * boast[t];
    float l1 = ssum * boast[256 + t];
    float lm = bredMax256(fmaxf(l0, l1), red);
    float e0 = expf(l0 - lm), e1 = expf(l1 - lm);
    float esum = bredSum256(e0 + e1, red);
    float w40 = e0 / esum, w41 = e1 / esum;
    if (t < 128) arow[(b << 7) + t] = w40;
    else acol[(b << 7) + (t - 128)] = w40;
    alpha[b * CC + t] = res_scale[0] + w41 * sig;
}

// ---------- S5row ----------
__global__ __launch_bounds__(128) void kS5r(const float* __restrict__ Usum, const float* __restrict__ w_row,
                                            const float* __restrict__ tm, float* __restrict__ attr) {
    int bh = blockIdx.x;
    int w = threadIdx.x;
    __shared__ float red[2];
    float l = Usum[bh] * w_row[w] + 0.5f * tm[bh];
    float m = l;
    for (int o = 32; o; o >>= 1) m = fmaxf(m, __shfl_xor(m, o));
    if ((w & 63) == 0) red[w >> 6] = m;
    __syncthreads();
    m = fmaxf(red[0], red[1]);
    __syncthreads();
    float e = expf(l - m);
    float s = e;
    for (int o = 32; o; o >>= 1) s += __shfl_xor(s, o);
    if ((w & 63) == 0) red[w >> 6] = s;
    __syncthreads();
    s = red[0] + red[1];
    attr[bh * 128 + w] = e / s;
}

// ---------- S5col ----------
__global__ __launch_bounds__(128) void kS5c(const float* __restrict__ Usum, const float* __restrict__ w_col,
                                            const float* __restrict__ tm, float* __restrict__ attc) {
    int bw = blockIdx.x; int b = bw >> 7, w = bw & 127;
    int h = threadIdx.x;
    __shared__ float red[2];
    float l = Usum[(b << 7) + h] * w_col[w] + 0.5f * tm[(b << 7) + h];
    float m = l;
    for (int o = 32; o; o >>= 1) m = fmaxf(m, __shfl_xor(m, o));
    if ((h & 63) == 0) red[h >> 6] = m;
    __syncthreads();
    m = fmaxf(red[0], red[1]);
    __syncthreads();
    float e = expf(l - m);
    float s = e;
    for (int o = 32; o; o >>= 1) s += __shfl_xor(s, o);
    if ((h & 63) == 0) red[h >> 6] = s;
    __syncthreads();
    s = red[0] + red[1];
    attc[((b << 7) + h) * 128 + w] = e / s;
}

// ---------- kR: R[b,c,h], Cctx[b,c,w] -> bf16 ----------
__global__ __launch_bounds__(128) void kR(const float* __restrict__ x, const float* __restrict__ attr,
                                          const float* __restrict__ attc, ushort* __restrict__ Rh,
                                          ushort* __restrict__ Ch) {
    int bc = blockIdx.x;
    int b = bc >> 8;
    int w = threadIdx.x;
    int lane = w & 63, wv = w >> 6;
    __shared__ float rp[128][2];
    float cacc = 0.f;
    const float* xt = x + (size_t)bc * PP;
    const float* ar = attr + b * PP;
    const float* ac = attc + b * PP;
    for (int h = 0; h < 128; ++h) {
        float xv = xt[h * 128 + w];
        float arv = ar[h * 128 + w];
        float acv = ac[h * 128 + w];
        cacc = fmaf(acv, xv, cacc);
        float r = arv * xv;
        for (int o = 32; o; o >>= 1) r += __shfl_down(r, o);
        if (lane == 0) rp[h][wv] = r;
    }
    __syncthreads();
    Ch[bc * 128 + w] = f2b(cacc);
    Rh[bc * 128 + w] = f2b(rp[w][0] + rp[w][1]);
}

// ---------- kF: MFMA GEMM (row_out/col_out) + epilogue ----------
// block: 64c x 128p (one h row), 4 waves (2c x 2p), wave: 32c x 64p
// A-frag: lane holds R[c = cbase + 16m + (l&15)][k = 32ks + 8(l>>4) + j]  (16B contiguous)
// B-frag: lane holds G[p = pbase + 16n + (l&15)][k = 32ks + 8(l>>4) + j]  (16B contiguous)
// D: row(c-offset) = 4*(l>>4)+reg, col(p-offset) = l&15   [verified layout]
__global__ __launch_bounds__(256) void kF(const float* __restrict__ x, const ushort* __restrict__ Rh,
                                          const ushort* __restrict__ Ch, const ushort* __restrict__ Gb,
                                          const float* __restrict__ Tg, const float* __restrict__ alpha,
                                          const float* __restrict__ sc, const float* __restrict__ sigmt,
                                          const float* __restrict__ arow, const float* __restrict__ acol,
                                          float* __restrict__ out) {
    int b = blockIdx.z;
    int c0 = blockIdx.y * 64;
    int p0 = blockIdx.x * 128;
    int tid = threadIdx.x;
    int wid = tid >> 6, l = tid & 63;
    int wy = wid >> 1, wx = wid & 1;
    int lr = l & 15, lk = l >> 4;
    int cbase = c0 + wy * 32;
    int pbase = p0 + wx * 64;

    f32x4 accR[2][4], accC[2][4];
    #pragma unroll
    for (int m = 0; m < 2; ++m)
        #pragma unroll
        for (int n = 0; n < 4; ++n) {
            accR[m][n] = (f32x4){0.f, 0.f, 0.f, 0.f};
            accC[m][n] = (f32x4){0.f, 0.f, 0.f, 0.f};
        }

    const ushort* Rbase = Rh + (((b << 8) + cbase + lr) << 7);
    const ushort* Cbase = Ch + (((b << 8) + cbase + lr) << 7);
    const ushort* Gbase = Gb + ((size_t)(pbase + lr) << 7);

    #pragma unroll
    for (int ks = 0; ks < 4; ++ks) {
        int ko = ks * 32 + lk * 8;
        bf16x8 aR0 = *(const bf16x8*)(Rbase + ko);
        bf16x8 aR1 = *(const bf16x8*)(Rbase + (16 << 7) + ko);
        bf16x8 aC0 = *(const bf16x8*)(Cbase + ko);
        bf16x8 aC1 = *(const bf16x8*)(Cbase + (16 << 7) + ko);
        bf16x8 bg0 = *(const bf16x8*)(Gbase + (0 << 11) + ko);
        bf16x8 bg1 = *(const bf16x8*)(Gbase + (1 << 11) + ko);
        bf16x8 bg2 = *(const bf16x8*)(Gbase + (2 << 11) + ko);
        bf16x8 bg3 = *(const bf16x8*)(Gbase + (3 << 11) + ko);
        accR[0][0] = __builtin_amdgcn_mfma_f32_16x16x32_bf16(aR0, bg0, accR[0][0], 0, 0, 0);
        accR[0][1] = __builtin_amdgcn_mfma_f32_16x16x32_bf16(aR0, bg1, accR[0][1], 0, 0, 0);
        accR[0][2] = __builtin_amdgcn_mfma_f32_16x16x32_bf16(aR0, bg2, accR[0][2], 0, 0, 0);
        accR[0][3] = __builtin_amdgcn_mfma_f32_16x16x32_bf16(aR0, bg3, accR[0][3], 0, 0, 0);
        accR[1][0] = __builtin_amdgcn_mfma_f32_16x16x32_bf16(aR1, bg0, accR[1][0], 0, 0, 0);
        accR[1][1] = __builtin_amdgcn_mfma_f32_16x16x32_bf16(aR1, bg1, accR[1][1], 0, 0, 0);
        accR[1][2] = __builtin_amdgcn_mfma_f32_16x16x32_bf16(aR1, bg2, accR[1][2], 0, 0, 0);
        accR[1][3] = __builtin_amdgcn_mfma_f32_16x16x32_bf16(aR1, bg3, accR[1][3], 0, 0, 0);
        accC[0][0] = __builtin_amdgcn_mfma_f32_16x16x32_bf16(aC0, bg0, accC[0][0], 0, 0, 0);
        accC[0][1] = __builtin_amdgcn_mfma_f32_16x16x32_bf16(aC0, bg1, accC[0][1], 0, 0, 0);
        accC[0][2] = __builtin_amdgcn_mfma_f32_16x16x32_bf16(aC0, bg2, accC[0][2], 0, 0, 0);
        accC[0][3] = __builtin_amdgcn_mfma_f32_16x16x32_bf16(aC0, bg3, accC[0][3], 0, 0, 0);
        accC[1][0] = __builtin_amdgcn_mfma_f32_16x16x32_bf16(aC1, bg0, accC[1][0], 0, 0, 0);
        accC[1][1] = __builtin_amdgcn_mfma_f32_16x16x32_bf16(aC1, bg1, accC[1][1], 0, 0, 0);
        accC[1][2] = __builtin_amdgcn_mfma_f32_16x16x32_bf16(aC1, bg2, accC[1][2], 0, 0, 0);
        accC[1][3] = __builtin_amdgcn_mfma_f32_16x16x32_bf16(aC1, bg3, accC[1][3], 0, 0, 0);
    }

    int h = p0 >> 7;
    float ar = arow[(b << 7) + h];
    float smt = sigmt[(b << 7) + h];
    float acw[4];
    #pragma unroll
    for (int n = 0; n < 4; ++n) acw[n] = acol[(b << 7) + wx * 64 + n * 16 + lr];

    #pragma unroll
    for (int m = 0; m < 2; ++m) {
        #pragma unroll
        for (int r = 0; r < 4; ++r) {
            int c = cbase + m * 16 + lk * 4 + r;
            float al = alpha[(b << 8) + c];
            float tb = (sc[(b << 8) + c] + smt) * Tg[(((b << 8) + c) << 7) + h];
            const float* xp = x + (((size_t)((b << 8) + c)) << 14) + ((size_t)h << 7);
            float* op = out + (((size_t)((b << 8) + c)) << 14) + ((size_t)h << 7);
            #pragma unroll
            for (int n = 0; n < 4; ++n) {
                int w = wx * 64 + n * 16 + lr;
                op[w] = fmaf(al, xp[w], fmaf(ar, accR[m][n][r], fmaf(acw[n], accC[m][n][r], ar * acw[n] * tb)));
            }
        }
    }
}

extern "C" void kernel_launch(void* const* d_in, const int* in_sizes, int n_in,
                              void* d_out, int out_size, void* d_ws, size_t ws_size,
                              hipStream_t stream) {
    const float* x        = (const float*)d_in[0];
    const float* U        = (const float*)d_in[1];
    const float* S        = (const float*)d_in[2];
    const float* V        = (const float*)d_in[3];
    const float* G        = (const float*)d_in[4];
    const float* w_row    = (const float*)d_in[5];
    const float* w_col    = (const float*)d_in[6];
    const float* boast    = (const float*)d_in[7];
    const float* res_scale= (const float*)d_in[8];
    const float* reduce_w = (const float*)d_in[9];
    const float* gcn_w    = (const float*)d_in[10];
    const float* gcn_b    = (const float*)d_in[11];
    const float* expand_w = (const float*)d_in[12];
    float* ws = (float*)d_ws;
    float* out = (float*)d_out;

    float* Xnode = ws + O_XNODE;
    float* Tg    = ws + O_T;
    ushort* Rh   = (ushort*)(ws + O_R);
    ushort* Ch   = (ushort*)(ws + O_CTX);
    ushort* Gb   = (ushort*)(ws + O_GT);
    float* attr  = ws + O_ATTR;
    float* attc  = ws + O_ATTC;
    float* Un    = ws + O_UN;
    float* sup   = ws + O_SUP;
    float* gout  = ws + O_GOUT;
    float* vals  = ws + O_VALS;
    float* deg   = ws + O_DEG;
    float* Usum  = ws + O_USUM;
    float* tmsum = ws + O_TMSUM;
    float* tm    = ws + O_TM;
    float* sigmt = ws + O_SIGMT;
    float* alpha = ws + O_ALPHA;
    float* sc    = ws + O_SC;
    float* arow  = ws + O_AROW;
    float* acol  = ws + O_ACOL;
    int*   idxv  = (int*)(ws + O_IDX);

    kGb<<<PP * 128 / (256 * 8), 256, 0, stream>>>(G, Gb);
    kA<<<BB * CC * HH / 4, 256, 0, stream>>>(x, Xnode);
    kS1<<<BB * HH, 64, 0, stream>>>(U, Xnode, reduce_w, gcn_w, Un, Usum, sup);
    kS2<<<BB * HH, 128, 0, stream>>>(Un, vals, idxv, deg);
    kS3<<<BB * HH, 64, 0, stream>>>(vals, idxv, deg, sup, gcn_b, expand_w, gout, Tg, tmsum, sigmt);
    kS4<<<BB, 256, 0, stream>>>(Xnode, Tg, V, S, boast, res_scale, w_row, w_col, tmsum,
                                tm, alpha, sc, arow, acol);
    kS5r<<<BB * HH, 128, 0, stream>>>(Usum, w_row, tm, attr);
    kS5c<<<BB * WW, 128, 0, stream>>>(Usum, w_col, tm, attc);
    kR<<<BB * CC, 128, 0, stream>>>(x, attr, attc, Rh, Ch);
    kF<<<dim3(PP / 128, CC / 64, BB), 256, 0, stream>>>(x, Rh, Ch, Gb, Tg, alpha, sc, sigmt,
                                                        arow, acol, out);
}

// Round 3
// 196.602 us; speedup vs baseline: 2.0717x; 1.3580x over previous
//
#include <hip/hip_runtime.h>
#include <math.h>

#define BB 8
#define CC 256
#define HH 128
#define WW 128
#define KK 16
#define GG 64
#define PP 16384  // H*W

typedef __attribute__((ext_vector_type(8))) short bf16x8;
typedef __attribute__((ext_vector_type(4))) float f32x4;

// ---------------- ws layout (float offsets) ----------------
#define O_XNODE   0u          // B*C*H = 262144
#define O_T       262144u     // 262144
#define O_R       524288u     // Rh bf16 (262144 ushort)
#define O_CTX     786432u     // Ch bf16
#define O_GT      1048576u    // Gb bf16 (2097152 ushort)
#define O_ATTR    3145728u    // B*H*W = 131072
#define O_ATTC    3276800u    // 131072
#define O_UN      3407872u    // B*H*16 = 16384
#define O_SUP     3424256u    // B*H*64 = 65536
#define O_GOUT    3489792u    // 65536
#define O_VALS    3555328u    // B*H*8 = 8192
#define O_DEG     3563520u    // 1024
#define O_USUM    3564544u    // 1024
#define O_TMSUM   3565568u    // 1024
#define O_TM      3566592u    // 1024
#define O_SIGMT   3567616u    // 1024
#define O_ALPHA   3568640u    // 2048
#define O_SC      3570688u    // 2048
#define O_AROW    3572736u    // 1024
#define O_ACOL    3573760u    // 1024
#define O_IDX     3574784u    // 8192 ints

__device__ __forceinline__ ushort f2b(float f) {
    unsigned u = __float_as_uint(f);
    unsigned r = (u + 0x7FFFu + ((u >> 16) & 1u)) >> 16;
    return (ushort)r;
}

__device__ __forceinline__ float bredSum256(float v, float* red) {
    int t = threadIdx.x, lane = t & 63, wv = t >> 6;
    for (int o = 32; o; o >>= 1) v += __shfl_xor(v, o);
    __syncthreads();
    if (lane == 0) red[wv] = v;
    __syncthreads();
    return red[0] + red[1] + red[2] + red[3];
}
__device__ __forceinline__ float bredMax256(float v, float* red) {
    int t = threadIdx.x, lane = t & 63, wv = t >> 6;
    for (int o = 32; o; o >>= 1) v = fmaxf(v, __shfl_xor(v, o));
    __syncthreads();
    if (lane == 0) red[wv] = v;
    __syncthreads();
    return fmaxf(fmaxf(red[0], red[1]), fmaxf(red[2], red[3]));
}

// ---------- kA: X_node mean over w  (+ merged G->bf16 convert in first 1024 blocks) ----------
__global__ __launch_bounds__(256) void kA(const float* __restrict__ x, float* __restrict__ Xnode,
                                          const float* __restrict__ G, ushort* __restrict__ Gb) {
    if (blockIdx.x < 1024) {
        int i = (blockIdx.x * 256 + threadIdx.x) * 8;
        float4 v0 = *(const float4*)&G[i];
        float4 v1 = *(const float4*)&G[i + 4];
        union { ushort us[8]; uint4 u4; } o;
        o.us[0] = f2b(v0.x); o.us[1] = f2b(v0.y); o.us[2] = f2b(v0.z); o.us[3] = f2b(v0.w);
        o.us[4] = f2b(v1.x); o.us[5] = f2b(v1.y); o.us[6] = f2b(v1.z); o.us[7] = f2b(v1.w);
        *(uint4*)&Gb[i] = o.u4;
        return;
    }
    int row = (blockIdx.x - 1024) * 4 + (threadIdx.x >> 6);
    int lane = threadIdx.x & 63;
    const float2 v = *(const float2*)&x[(size_t)row * 128 + lane * 2];
    float s = v.x + v.y;
    for (int o = 32; o; o >>= 1) s += __shfl_down(s, o);
    if (lane == 0) Xnode[row] = s * (1.0f / 128.0f);
}

// ---------- S1: Un, Usum, support (per b,h) ----------
__global__ __launch_bounds__(64) void kS1(const float* __restrict__ U, const float* __restrict__ Xnode,
                                          const float* __restrict__ reduce_w, const float* __restrict__ gcn_w,
                                          float* __restrict__ Un, float* __restrict__ Usum, float* __restrict__ sup) {
    int bh = blockIdx.x; int b = bh >> 7, h = bh & 127;
    int t = threadIdx.x;
    __shared__ float xr[64];
    float u = (t < 16) ? U[bh * 16 + t] : 0.f;
    float ss = u * u;
    for (int o = 8; o; o >>= 1) ss += __shfl_xor(ss, o, 16);
    float us = u;
    for (int o = 8; o; o >>= 1) us += __shfl_xor(us, o, 16);
    if (t < 16) Un[bh * 16 + t] = u / fmaxf(sqrtf(ss), 1e-12f);
    if (t == 0) Usum[bh] = us;
    float acc = 0.f;
    #pragma unroll
    for (int m = 0; m < 4; ++m)
        acc = fmaf(Xnode[((b * CC + t * 4 + m) << 7) + h], reduce_w[t * 4 + m], acc);
    xr[t] = acc;
    __syncthreads();
    float sp = 0.f;
    for (int g = 0; g < 64; ++g) sp = fmaf(xr[g], gcn_w[g * 64 + t], sp);
    sup[bh * 64 + t] = sp;
}

// ---------- S2: sim row + top-8 + deg (per b,i) ----------
__global__ __launch_bounds__(128) void kS2(const float* __restrict__ Un, float* __restrict__ vals,
                                           int* __restrict__ idxv, float* __restrict__ deg) {
    int bh = blockIdx.x; int b = bh >> 7;
    int t = threadIdx.x;
    __shared__ float uni[16];
    __shared__ unsigned long long wmax[2];
    if (t < 16) uni[t] = Un[bh * 16 + t];
    __syncthreads();
    const float* uj = Un + (b << 11) + t * 16;
    float s = 0.f;
    #pragma unroll
    for (int q = 0; q < 16; ++q) s = fmaf(uni[q], uj[q], s);
    float dsum = 0.f;
    for (int r = 0; r < 8; ++r) {
        unsigned m = __float_as_uint(s);
        m = (m & 0x80000000u) ? ~m : (m | 0x80000000u);
        unsigned long long key = ((unsigned long long)m << 32) | (unsigned)(0xFFFFFFFFu - (unsigned)t);
        for (int o = 32; o; o >>= 1) { unsigned long long ok = __shfl_xor(key, o); key = key > ok ? key : ok; }
        if ((t & 63) == 0) wmax[t >> 6] = key;
        __syncthreads();
        unsigned long long kk = wmax[0] > wmax[1] ? wmax[0] : wmax[1];
        __syncthreads();
        int jw = (int)(0xFFFFFFFFu - (unsigned)(kk & 0xFFFFFFFFu));
        unsigned mm = (unsigned)(kk >> 32);
        mm = (mm & 0x80000000u) ? (mm & 0x7FFFFFFFu) : ~mm;
        float vw = __uint_as_float(mm);
        dsum += vw;
        if (t == r) { vals[bh * 8 + r] = vw; idxv[bh * 8 + r] = jw; }
        if (t == jw) s = -3.4e38f;
    }
    if (t == 0) deg[bh] = dsum;
}

// ---------- S3: gout, T, tmsum, sigmt (per b,i) ----------
__global__ __launch_bounds__(64) void kS3(const float* __restrict__ vals, const int* __restrict__ idxv,
                                          const float* __restrict__ deg, const float* __restrict__ sup,
                                          const float* __restrict__ gcn_b, const float* __restrict__ expand_w,
                                          float* __restrict__ gout, float* __restrict__ Tg,
                                          float* __restrict__ tmsum, float* __restrict__ sigmt) {
    int bh = blockIdx.x; int b = bh >> 7, i = bh & 127;
    int t = threadIdx.x;
    __shared__ float coef[8];
    __shared__ int id[8];
    if (t < 8) {
        int j = idxv[bh * 8 + t];
        float dv = vals[bh * 8 + t] * (1.f / sqrtf(deg[bh])) * (1.f / sqrtf(deg[(b << 7) + j]));
        coef[t] = dv; id[t] = j;
    }
    __syncthreads();
    float acc = gcn_b[t];
    #pragma unroll
    for (int q = 0; q < 8; ++q) acc = fmaf(coef[q], sup[((b << 7) + id[q]) * 64 + t], acc);
    float go = fmaxf(acc, 0.f);
    gout[bh * 64 + t] = go;
    float e0 = expand_w[t * 4], e1 = expand_w[t * 4 + 1], e2 = expand_w[t * 4 + 2], e3 = expand_w[t * 4 + 3];
    Tg[((b * CC + t * 4 + 0) << 7) + i] = go * e0;
    Tg[((b * CC + t * 4 + 1) << 7) + i] = go * e1;
    Tg[((b * CC + t * 4 + 2) << 7) + i] = go * e2;
    Tg[((b * CC + t * 4 + 3) << 7) + i] = go * e3;
    float tms = fabsf(go) * (fabsf(e0) + fabsf(e1) + fabsf(e2) + fabsf(e3));
    float mtp = go * (e0 + e1 + e2 + e3);
    for (int o = 32; o; o >>= 1) { tms += __shfl_down(tms, o); mtp += __shfl_down(mtp, o); }
    if (t == 0) {
        tmsum[bh] = tms;
        sigmt[bh] = 1.f / (1.f + expf(-(mtp * (1.f / 256.f))));
    }
}

// ---------- S4: tm, z's, ch_rec/sig, sc, w4 -> arow/acol/alpha (per b) ----------
__global__ __launch_bounds__(256) void kS4(const float* __restrict__ Xnode, const float* __restrict__ Tg,
                                           const float* __restrict__ V, const float* __restrict__ S,
                                           const float* __restrict__ boast, const float* __restrict__ res_scale,
                                           const float* __restrict__ w_row, const float* __restrict__ w_col,
                                           const float* __restrict__ tmsum,
                                           float* __restrict__ tm, float* __restrict__ alpha, float* __restrict__ sc,
                                           float* __restrict__ arow, float* __restrict__ acol) {
    int b = blockIdx.x; int t = threadIdx.x;
    __shared__ float red[4];
    __shared__ float zc[256];
    __shared__ float zk[16];
    float tv = (t < 128) ? tmsum[(b << 7) + t] : -3.4e38f;
    float tmax = bredMax256(tv, red);
    if (t < 128) tm[(b << 7) + t] = tv / fmaxf(tmax, 1e-6f);
    const float* xn = Xnode + ((size_t)(b * CC + t) << 7);
    const float* tg = Tg + ((size_t)(b * CC + t) << 7);
    float zx = 0.f, zt = 0.f;
    for (int h = 0; h < 128; h += 4) {
        float4 a = *(const float4*)&xn[h];
        float4 bq = *(const float4*)&tg[h];
        zx += (a.x + a.y) + (a.z + a.w);
        zt += (bq.x + bq.y) + (bq.z + bq.w);
    }
    zx *= (1.f / 128.f); zt *= (1.f / 128.f);
    zc[t] = zx + 0.5f * zt;
    __syncthreads();
    if (t < 16) {
        float a = 0.f;
        for (int c = 0; c < 256; ++c) a = fmaf(zc[c], V[((b * CC + c) << 4) + t], a);
        zk[t] = a;
    }
    __syncthreads();
    float sumS = 0.f, sumz = 0.f;
    #pragma unroll
    for (int j = 0; j < 16; ++j) { sumS += S[(b << 4) + j]; sumz += zk[j]; }
    float Vz = 0.f, VS = 0.f;
    #pragma unroll
    for (int j = 0; j < 16; ++j) {
        float vv = V[((b * CC + t) << 4) + j];
        Vz = fmaf(vv, zk[j], Vz);
        VS = fmaf(vv, S[(b << 4) + j], VS);
    }
    float ch = (Vz * sumS + VS * sumz) * (1.f / 32.f);
    float sig = 1.f / (1.f + expf(-ch));
    float zm = bredMax256(zt, red);
    float e = expf(zt - zm);
    float es = bredSum256(e, red);
    sc[b * CC + t] = e / es;
    float ps = 0.f;
    for (int q = t; q < 272; q += 256) {
        float si = (q < 16) ? S[(b << 4) + q] : (q < 144 ? w_col[q - 16] : w_row[q - 144]);
        ps += si;
    }
    float ssum = bredSum256(ps, red);
    float l0 = ssum * boast[t];
    float l1 = ssum * boast[256 + t];
    float lm = bredMax256(fmaxf(l0, l1), red);
    float e0 = expf(l0 - lm), e1 = expf(l1 - lm);
    float esum = bredSum256(e0 + e1, red);
    float w40 = e0 / esum, w41 = e1 / esum;
    if (t < 128) arow[(b << 7) + t] = w40;
    else acol[(b << 7) + (t - 128)] = w40;
    alpha[b * CC + t] = res_scale[0] + w41 * sig;
}

// ---------- S5: merged row/col softmax ----------
__global__ __launch_bounds__(128) void kS5(const float* __restrict__ Usum, const float* __restrict__ w_row,
                                           const float* __restrict__ w_col, const float* __restrict__ tm,
                                           float* __restrict__ attr, float* __restrict__ attc) {
    __shared__ float red[2];
    int id = blockIdx.x;
    int t = threadIdx.x;
    if (id < BB * HH) {
        int bh = id;
        float l = Usum[bh] * w_row[t] + 0.5f * tm[bh];
        float m = l;
        for (int o = 32; o; o >>= 1) m = fmaxf(m, __shfl_xor(m, o));
        if ((t & 63) == 0) red[t >> 6] = m;
        __syncthreads();
        m = fmaxf(red[0], red[1]);
        __syncthreads();
        float e = expf(l - m);
        float s = e;
        for (int o = 32; o; o >>= 1) s += __shfl_xor(s, o);
        if ((t & 63) == 0) red[t >> 6] = s;
        __syncthreads();
        s = red[0] + red[1];
        attr[bh * 128 + t] = e / s;
    } else {
        int bw = id - BB * HH; int b = bw >> 7, w = bw & 127;
        float l = Usum[(b << 7) + t] * w_col[w] + 0.5f * tm[(b << 7) + t];
        float m = l;
        for (int o = 32; o; o >>= 1) m = fmaxf(m, __shfl_xor(m, o));
        if ((t & 63) == 0) red[t >> 6] = m;
        __syncthreads();
        m = fmaxf(red[0], red[1]);
        __syncthreads();
        float e = expf(l - m);
        float s = e;
        for (int o = 32; o; o >>= 1) s += __shfl_xor(s, o);
        if ((t & 63) == 0) red[t >> 6] = s;
        __syncthreads();
        s = red[0] + red[1];
        attc[((b << 7) + t) * 128 + w] = e / s;
    }
}

// ---------- kR: R[b,c,h], Cctx[b,c,w] -> bf16  (LDS-tiled, coalesced) ----------
__global__ __launch_bounds__(256) void kR(const float* __restrict__ x, const float* __restrict__ attr,
                                          const float* __restrict__ attc, ushort* __restrict__ Rh,
                                          ushort* __restrict__ Ch) {
    int bc = blockIdx.x;
    int b = bc >> 8;
    int t = threadIdx.x;
    __shared__ float tile[64][132];   // ar*x staged; stride 132 -> b128 reads hit all banks evenly
    __shared__ float rsum[64][5];     // +1 pad
    __shared__ float cred[8][128];
    int wq = (t & 31) * 4;            // w quad base
    int hg = t >> 5;                  // h-group 0..7
    const float* xb  = x    + (size_t)bc * PP;
    const float* arb = attr + (size_t)b * PP;
    const float* acb = attc + (size_t)b * PP;
    float4 cacc = make_float4(0.f, 0.f, 0.f, 0.f);
    #pragma unroll
    for (int cchunk = 0; cchunk < 2; ++cchunk) {
        int h0 = cchunk * 64;
        #pragma unroll
        for (int i = 0; i < 8; ++i) {
            int hh = i * 8 + hg;
            int off = (h0 + hh) * 128 + wq;
            float4 xv  = *(const float4*)&xb[off];
            float4 ar4 = *(const float4*)&arb[off];
            float4 ac4 = *(const float4*)&acb[off];
            cacc.x = fmaf(ac4.x, xv.x, cacc.x);
            cacc.y = fmaf(ac4.y, xv.y, cacc.y);
            cacc.z = fmaf(ac4.z, xv.z, cacc.z);
            cacc.w = fmaf(ac4.w, xv.w, cacc.w);
            float4 pr;
            pr.x = ar4.x * xv.x; pr.y = ar4.y * xv.y; pr.z = ar4.z * xv.z; pr.w = ar4.w * xv.w;
            *(float4*)&tile[hh][wq] = pr;
        }
        __syncthreads();
        int hl = t & 63, q = t >> 6;
        float s = 0.f;
        #pragma unroll
        for (int j = 0; j < 8; ++j) {
            float4 v = *(const float4*)&tile[hl][q * 32 + j * 4];
            s += (v.x + v.y) + (v.z + v.w);
        }
        rsum[hl][q] = s;
        __syncthreads();
        if (t < 64) Rh[bc * 128 + h0 + t] = f2b(rsum[t][0] + rsum[t][1] + rsum[t][2] + rsum[t][3]);
        __syncthreads();
    }
    *(float4*)&cred[hg][wq] = cacc;
    __syncthreads();
    if (t < 128) {
        float s = 0.f;
        #pragma unroll
        for (int g = 0; g < 8; ++g) s += cred[g][t];
        Ch[bc * 128 + t] = f2b(s);
    }
}

// ---------- kF: MFMA GEMM + epilogue, SWAPPED operands (A=G rows=p, B=R/C rows=c) ----------
// D layout: col = lane&15 -> c offset; row = 4*(lane>>4)+reg -> p offset.
// => per lane, acc[m][n] is float4 over 4 CONSECUTIVE p at fixed c: float4 epilogue.
__global__ __launch_bounds__(256) void kF(const float* __restrict__ x, const ushort* __restrict__ Rh,
                                          const ushort* __restrict__ Ch, const ushort* __restrict__ Gb,
                                          const float* __restrict__ Tg, const float* __restrict__ alpha,
                                          const float* __restrict__ sc, const float* __restrict__ sigmt,
                                          const float* __restrict__ arow, const float* __restrict__ acol,
                                          float* __restrict__ out) {
    int b = blockIdx.z;
    int c0 = blockIdx.y * 64;
    int p0 = blockIdx.x * 128;
    int tid = threadIdx.x;
    int wid = tid >> 6, l = tid & 63;
    int lr = l & 15, lk = l >> 4;
    int pbase = p0 + (wid & 1) * 64;   // wave: 64p x 32c
    int cbase = c0 + (wid >> 1) * 32;

    f32x4 accR[4][2], accC[4][2];
    #pragma unroll
    for (int m = 0; m < 4; ++m)
        #pragma unroll
        for (int n = 0; n < 2; ++n) {
            accR[m][n] = (f32x4){0.f, 0.f, 0.f, 0.f};
            accC[m][n] = (f32x4){0.f, 0.f, 0.f, 0.f};
        }

    const ushort* Gbase = Gb + ((size_t)(pbase + lr) << 7);
    const ushort* Rbase = Rh + (((b << 8) + cbase + lr) << 7);
    const ushort* Cbase = Ch + (((b << 8) + cbase + lr) << 7);

    #pragma unroll
    for (int ks = 0; ks < 4; ++ks) {
        int ko = ks * 32 + lk * 8;
        bf16x8 ag0 = *(const bf16x8*)(Gbase + (0 << 11) + ko);
        bf16x8 ag1 = *(const bf16x8*)(Gbase + (1 << 11) + ko);
        bf16x8 ag2 = *(const bf16x8*)(Gbase + (2 << 11) + ko);
        bf16x8 ag3 = *(const bf16x8*)(Gbase + (3 << 11) + ko);
        bf16x8 bR0 = *(const bf16x8*)(Rbase + ko);
        bf16x8 bR1 = *(const bf16x8*)(Rbase + (16 << 7) + ko);
        bf16x8 bC0 = *(const bf16x8*)(Cbase + ko);
        bf16x8 bC1 = *(const bf16x8*)(Cbase + (16 << 7) + ko);
        accR[0][0] = __builtin_amdgcn_mfma_f32_16x16x32_bf16(ag0, bR0, accR[0][0], 0, 0, 0);
        accR[0][1] = __builtin_amdgcn_mfma_f32_16x16x32_bf16(ag0, bR1, accR[0][1], 0, 0, 0);
        accR[1][0] = __builtin_amdgcn_mfma_f32_16x16x32_bf16(ag1, bR0, accR[1][0], 0, 0, 0);
        accR[1][1] = __builtin_amdgcn_mfma_f32_16x16x32_bf16(ag1, bR1, accR[1][1], 0, 0, 0);
        accR[2][0] = __builtin_amdgcn_mfma_f32_16x16x32_bf16(ag2, bR0, accR[2][0], 0, 0, 0);
        accR[2][1] = __builtin_amdgcn_mfma_f32_16x16x32_bf16(ag2, bR1, accR[2][1], 0, 0, 0);
        accR[3][0] = __builtin_amdgcn_mfma_f32_16x16x32_bf16(ag3, bR0, accR[3][0], 0, 0, 0);
        accR[3][1] = __builtin_amdgcn_mfma_f32_16x16x32_bf16(ag3, bR1, accR[3][1], 0, 0, 0);
        accC[0][0] = __builtin_amdgcn_mfma_f32_16x16x32_bf16(ag0, bC0, accC[0][0], 0, 0, 0);
        accC[0][1] = __builtin_amdgcn_mfma_f32_16x16x32_bf16(ag0, bC1, accC[0][1], 0, 0, 0);
        accC[1][0] = __builtin_amdgcn_mfma_f32_16x16x32_bf16(ag1, bC0, accC[1][0], 0, 0, 0);
        accC[1][1] = __builtin_amdgcn_mfma_f32_16x16x32_bf16(ag1, bC1, accC[1][1], 0, 0, 0);
        accC[2][0] = __builtin_amdgcn_mfma_f32_16x16x32_bf16(ag2, bC0, accC[2][0], 0, 0, 0);
        accC[2][1] = __builtin_amdgcn_mfma_f32_16x16x32_bf16(ag2, bC1, accC[2][1], 0, 0, 0);
        accC[3][0] = __builtin_amdgcn_mfma_f32_16x16x32_bf16(ag3, bC0, accC[3][0], 0, 0, 0);
        accC[3][1] = __builtin_amdgcn_mfma_f32_16x16x32_bf16(ag3, bC1, accC[3][1], 0, 0, 0);
    }

    int h = p0 >> 7;                    // one h row per block
    float ar = arow[(b << 7) + h];
    float smt = sigmt[(b << 7) + h];
    int wloc = (wid & 1) * 64 + 4 * lk; // (p & 127) base for this lane
    f32x4 acw[4];
    #pragma unroll
    for (int m = 0; m < 4; ++m) acw[m] = *(const f32x4*)&acol[(b << 7) + wloc + 16 * m];

    #pragma unroll
    for (int n = 0; n < 2; ++n) {
        int c = cbase + 16 * n + lr;
        float al = alpha[(b << 8) + c];
        float tb = (sc[(b << 8) + c] + smt) * Tg[(((b << 8) + c) << 7) + h];
        size_t rowbase = ((size_t)((b << 8) + c) << 14) + pbase + 4 * lk;
        #pragma unroll
        for (int m = 0; m < 4; ++m) {
            size_t off = rowbase + 16 * m;
            float4 xv = *(const float4*)&x[off];
            float4 o;
            o.x = fmaf(al, xv.x, fmaf(ar, accR[m][n][0], fmaf(acw[m][0], accC[m][n][0], ar * acw[m][0] * tb)));
            o.y = fmaf(al, xv.y, fmaf(ar, accR[m][n][1], fmaf(acw[m][1], accC[m][n][1], ar * acw[m][1] * tb)));
            o.z = fmaf(al, xv.z, fmaf(ar, accR[m][n][2], fmaf(acw[m][2], accC[m][n][2], ar * acw[m][2] * tb)));
            o.w = fmaf(al, xv.w, fmaf(ar, accR[m][n][3], fmaf(acw[m][3], accC[m][n][3], ar * acw[m][3] * tb)));
            *(float4*)&out[off] = o;
        }
    }
}

extern "C" void kernel_launch(void* const* d_in, const int* in_sizes, int n_in,
                              void* d_out, int out_size, void* d_ws, size_t ws_size,
                              hipStream_t stream) {
    const float* x        = (const float*)d_in[0];
    const float* U        = (const float*)d_in[1];
    const float* S        = (const float*)d_in[2];
    const float* V        = (const float*)d_in[3];
    const float* G        = (const float*)d_in[4];
    const float* w_row    = (const float*)d_in[5];
    const float* w_col    = (const float*)d_in[6];
    const float* boast    = (const float*)d_in[7];
    const float* res_scale= (const float*)d_in[8];
    const float* reduce_w = (const float*)d_in[9];
    const float* gcn_w    = (const float*)d_in[10];
    const float* gcn_b    = (const float*)d_in[11];
    const float* expand_w = (const float*)d_in[12];
    float* ws = (float*)d_ws;
    float* out = (float*)d_out;

    float* Xnode = ws + O_XNODE;
    float* Tg    = ws + O_T;
    ushort* Rh   = (ushort*)(ws + O_R);
    ushort* Ch   = (ushort*)(ws + O_CTX);
    ushort* Gb   = (ushort*)(ws + O_GT);
    float* attr  = ws + O_ATTR;
    float* attc  = ws + O_ATTC;
    float* Un    = ws + O_UN;
    float* sup   = ws + O_SUP;
    float* gout  = ws + O_GOUT;
    float* vals  = ws + O_VALS;
    float* deg   = ws + O_DEG;
    float* Usum  = ws + O_USUM;
    float* tmsum = ws + O_TMSUM;
    float* tm    = ws + O_TM;
    float* sigmt = ws + O_SIGMT;
    float* alpha = ws + O_ALPHA;
    float* sc    = ws + O_SC;
    float* arow  = ws + O_AROW;
    float* acol  = ws + O_ACOL;
    int*   idxv  = (int*)(ws + O_IDX);

    kA<<<1024 + BB * CC * HH / 4, 256, 0, stream>>>(x, Xnode, G, Gb);
    kS1<<<BB * HH, 64, 0, stream>>>(U, Xnode, reduce_w, gcn_w, Un, Usum, sup);
    kS2<<<BB * HH, 128, 0, stream>>>(Un, vals, idxv, deg);
    kS3<<<BB * HH, 64, 0, stream>>>(vals, idxv, deg, sup, gcn_b, expand_w, gout, Tg, tmsum, sigmt);
    kS4<<<BB, 256, 0, stream>>>(Xnode, Tg, V, S, boast, res_scale, w_row, w_col, tmsum,
                                tm, alpha, sc, arow, acol);
    kS5<<<BB * HH + BB * WW, 128, 0, stream>>>(Usum, w_row, w_col, tm, attr, attc);
    kR<<<BB * CC, 256, 0, stream>>>(x, attr, attc, Rh, Ch);
    kF<<<dim3(PP / 128, CC / 64, BB), 256, 0, stream>>>(x, Rh, Ch, Gb, Tg, alpha, sc, sigmt,
                                                        arow, acol, out);
}